// Round 17
// baseline (1620.701 us; speedup 1.0000x reference)
//
#include <hip/hip_runtime.h>
#include <hip/hip_bf16.h>

typedef __bf16 bf16_t;
typedef bf16_t bf16x8 __attribute__((ext_vector_type(8)));
typedef bf16_t bf16x4 __attribute__((ext_vector_type(4)));
typedef float f32x4 __attribute__((ext_vector_type(4)));
typedef float f32x2 __attribute__((ext_vector_type(2)));

// ---------------------------------------------------------------------------
__device__ __forceinline__ void load_lds16(const bf16_t* g, bf16_t* l) {
  __builtin_amdgcn_global_load_lds(
      (const __attribute__((address_space(1))) unsigned int*)g,
      (__attribute__((address_space(3))) unsigned int*)l,
      16, 0, 0);
}

// ---------------------------------------------------------------------------
__global__ void conv_f32_bf16(const float* __restrict__ src,
                              bf16_t* __restrict__ dst, long n) {
  long i = ((long)blockIdx.x * blockDim.x + threadIdx.x) * 8;
  if (i + 7 >= n) return;
  float4 a = *(const float4*)(src + i);
  float4 b = *(const float4*)(src + i + 4);
  bf16x8 v;
  v[0] = (bf16_t)a.x; v[1] = (bf16_t)a.y; v[2] = (bf16_t)a.z; v[3] = (bf16_t)a.w;
  v[4] = (bf16_t)b.x; v[5] = (bf16_t)b.y; v[6] = (bf16_t)b.z; v[7] = (bf16_t)b.w;
  *(bf16x8*)(dst + i) = v;
}

__global__ void conv_bf16_f32(const bf16_t* __restrict__ src,
                              float* __restrict__ dst, long n) {
  long i = (long)blockIdx.x * blockDim.x + threadIdx.x;
  if (i >= n) return;
  dst[i] = (float)src[i];
}

__global__ void transpose_conv(const float* __restrict__ src,
                               bf16_t* __restrict__ dst, int Ksrc, int Nsrc) {
  __shared__ float tile[32][33];
  int n0 = blockIdx.x * 32, k0 = blockIdx.y * 32;
  int tx = threadIdx.x, ty = threadIdx.y;  // (32, 8)
#pragma unroll
  for (int i = 0; i < 32; i += 8)
    tile[ty + i][tx] = src[(long)(k0 + ty + i) * Nsrc + n0 + tx];
  __syncthreads();
#pragma unroll
  for (int i = 0; i < 32; i += 8)
    dst[(long)(n0 + ty + i) * Ksrc + k0 + tx] = (bf16_t)tile[tx][ty + i];
}

// ---------------------------------------------------------------------------
__device__ __forceinline__ void half_bar(unsigned int* c, unsigned int target,
                                         int lane) {
  if (lane == 0)
    __hip_atomic_fetch_add(c, 1u, __ATOMIC_RELEASE,
                           __HIP_MEMORY_SCOPE_WORKGROUP);
  unsigned int v;
  do {
    v = __hip_atomic_load(c, __ATOMIC_ACQUIRE, __HIP_MEMORY_SCOPE_WORKGROUP);
    if (v >= target) break;
    __builtin_amdgcn_s_sleep(1);
  } while (true);
}

// ---------------------------------------------------------------------------
// Persistent recurrence v15 = v14 (proven 1564us) + FUSED X-PROJECTION:
// Z_t = x_t @ W_xh is computed IN-STEP, accumulated into the SAME acc regs
// before the W_hh MFMAs (identical 16x32 tile shape).  W_xh slice (32 cols x
// K-slab 256) pinned in 16 more named bf16x8 (64 VGPR; total pinned 128).
// x A-frags (8 loads) issued PRE-POLL (static data; latency hides under the
// wait); x-MFMAs run before h-frag registers are allocated (peak-live ~215).
// h-epilogue adds b_h (register) instead of reading Z from memory.
// GEMM1 + Z traffic + Z prefetch DELETED.  Everything else (poll protocol,
// rotating epilogues, fused Q-projection, post-loop out_255): v14-identical.
// ---------------------------------------------------------------------------
__global__ __launch_bounds__(512, 1) void rnn_persistent15(
    const bf16_t* __restrict__ h0,
    const bf16_t* __restrict__ xb,    // (T*B, 1024) bf16
    bf16_t* __restrict__ Hbuf,        // h out, (T,B,H) bf16
    const bf16_t* __restrict__ WhhT,  // (2048 cols, 2048 K) bf16
    const bf16_t* __restrict__ WxhT,  // (2048 cols, 1024 K) bf16
    const float* __restrict__ bh,     // (2048,)
    const bf16_t* __restrict__ WhqT,  // (1024 qcols, 2048 K) bf16
    const float* __restrict__ bq,     // (1024,)
    float* __restrict__ out,          // (T*B, 1024) fp32
    unsigned int* __restrict__ flags) {  // 512 flags, 64B apart, pre-zeroed
  __shared__ bf16_t Wlds[65536];          // 128 KB
  __shared__ float sred[2][4][16 * 36];   // 18.4 KB
  __shared__ bf16_t qred[2][4][16 * 20];  // 5 KB
  __shared__ unsigned int barc[2];
  __shared__ unsigned int sfree[2];
  __shared__ unsigned int qbc[2];
  __shared__ unsigned int qfree[2];

  const int tid = threadIdx.x, lane = tid & 63, w = tid >> 6;
  const int h = w >> 2;               // half 0/1
  const int lw = w & 3;               // wave within half
  const int gid = blockIdx.x;
  const int p = (gid >> 1) & 3;
  const int n0idx = ((gid & 1) << 5) | (gid >> 3);  // 0..63
  const int chain = p + h * 4;        // row group 0..7
  const int m0 = chain * 16, n0 = n0idx * 32;
  const int H = 2048;
  const long BH = 128L * 2048;
  const int kb = lw * 512;            // wave K-slab (W_hh, K=2048)
  const int kbx = lw * 256;           // wave K-slab (W_xh, K=1024)
  const int fr = lane & 15, fg = lane >> 4;
  const int w64 = lw * 64;
  const int qcol0 = n0idx * 16;

  // ---- stage W_hh cols [n0, n0+32) into LDS (once) ----
  {
    const int scol = tid >> 4;
    const int sk16 = tid & 15;
    const bf16_t* gsrc = WhhT + (long)(n0 + scol) * H + sk16 * 8;
#pragma unroll 4
    for (int j = 0; j < 16; ++j) {
      bf16x8 v = *(const bf16x8*)(gsrc + j * 128);
      int k8 = sk16 + j * 16;
      *(bf16x8*)&Wlds[(k8 * 32 + scol) * 8] = v;
    }
  }
  if (tid < 2) { barc[tid] = 0; sfree[tid] = 0; qbc[tid] = 0; qfree[tid] = 0; }

#define LOADPIN(dst, addr)                                                    \
  bf16x8 dst = *(const bf16x8*)(addr);                                        \
  {                                                                           \
    f32x4 t_ = __builtin_bit_cast(f32x4, dst);                                \
    asm volatile("" : "+v"(t_));                                              \
    dst = __builtin_bit_cast(bf16x8, t_);                                     \
  }
  // ---- W_hq slice pinned: 16 named bf16x8 ----
  const bf16_t* Wq = WhqT + (long)(qcol0 + fr) * H + kb + fg * 8;
  LOADPIN(q0, Wq + 0)    LOADPIN(q1, Wq + 32)   LOADPIN(q2, Wq + 64)
  LOADPIN(q3, Wq + 96)   LOADPIN(q4, Wq + 128)  LOADPIN(q5, Wq + 160)
  LOADPIN(q6, Wq + 192)  LOADPIN(q7, Wq + 224)  LOADPIN(q8, Wq + 256)
  LOADPIN(q9, Wq + 288)  LOADPIN(q10, Wq + 320) LOADPIN(q11, Wq + 352)
  LOADPIN(q12, Wq + 384) LOADPIN(q13, Wq + 416) LOADPIN(q14, Wq + 448)
  LOADPIN(q15, Wq + 480)
  // ---- W_xh slice pinned: 16 named bf16x8 (cols n0+cf*16+fr, K-slab 256) --
  const bf16_t* Wx0 = WxhT + (long)(n0 + fr) * 1024 + kbx + fg * 8;
  const bf16_t* Wx1 = WxhT + (long)(n0 + 16 + fr) * 1024 + kbx + fg * 8;
  LOADPIN(wx0, Wx0 + 0)   LOADPIN(wx1, Wx0 + 32)  LOADPIN(wx2, Wx0 + 64)
  LOADPIN(wx3, Wx0 + 96)  LOADPIN(wx4, Wx0 + 128) LOADPIN(wx5, Wx0 + 160)
  LOADPIN(wx6, Wx0 + 192) LOADPIN(wx7, Wx0 + 224)
  LOADPIN(wy0, Wx1 + 0)   LOADPIN(wy1, Wx1 + 32)  LOADPIN(wy2, Wx1 + 64)
  LOADPIN(wy3, Wx1 + 96)  LOADPIN(wy4, Wx1 + 128) LOADPIN(wy5, Wx1 + 160)
  LOADPIN(wy6, Wx1 + 192) LOADPIN(wy7, Wx1 + 224)
#undef LOADPIN
  __syncthreads();

  if (h == 1) __builtin_amdgcn_s_sleep(64);

  // h-epilogue ownership: lane e -> row e>>2, cols (e&3)*8..+8
  const int zrowW = lane >> 2, zcolW = (lane & 3) * 8;
  const int sidx = zrowW * 36 + zcolW;
  const long zoffW = (long)(m0 + zrowW) * H + n0 + zcolW;
  const f32x4 bhlo = *(const f32x4*)(bh + n0 + zcolW);
  const f32x4 bhhi = *(const f32x4*)(bh + n0 + zcolW + 4);

  // q-epilogue ownership
  const int qrow = lane >> 2, qc4 = (lane & 3) * 4;
  const f32x4 bqv = *(const f32x4*)(bq + qcol0 + qc4);

  unsigned int* myflag = flags + (((chain << 6) | n0idx) << 4);
  const unsigned int* pollflag =
      flags + (((chain << 6) | (lw * 16 + (lane & 15))) << 4);
  unsigned int* bc = &barc[h];
  unsigned int* sf = &sfree[h];
  unsigned int* qc = &qbc[h];
  unsigned int* qf = &qfree[h];

  for (int t = 0; t < 256; ++t) {
    const bf16_t* hp = (t == 0) ? h0 : Hbuf + (long)(t - 1) * BH;
    bf16_t* z = Hbuf + (long)t * BH;
    const int ew = t & 3;          // h-epilogue wave
    const int ew2 = (t + 2) & 3;   // q-epilogue wave

    // ---- x A-frags: issued PRE-POLL (static data, latency under wait) ----
    const bf16_t* Xb = xb + ((long)t * 128 + m0 + fr) * 1024 + kbx + fg * 8;
    f32x4 x0, x1, x2, x3, x4, x5, x6, x7;
    asm volatile(
        "global_load_dwordx4 %0, %8, off sc0\n\t"
        "global_load_dwordx4 %1, %8, off offset:64 sc0\n\t"
        "global_load_dwordx4 %2, %8, off offset:128 sc0\n\t"
        "global_load_dwordx4 %3, %8, off offset:192 sc0\n\t"
        "global_load_dwordx4 %4, %8, off offset:256 sc0\n\t"
        "global_load_dwordx4 %5, %8, off offset:320 sc0\n\t"
        "global_load_dwordx4 %6, %8, off offset:384 sc0\n\t"
        "global_load_dwordx4 %7, %8, off offset:448 sc0"
        : "=&v"(x0), "=&v"(x1), "=&v"(x2), "=&v"(x3), "=&v"(x4), "=&v"(x5),
          "=&v"(x6), "=&v"(x7)
        : "v"(Xb)
        : "memory");

    // ---- poll my K-slab's 16 producer flags, light backoff ----
    if (t > 0) {
      const unsigned int tt = (unsigned int)t;
      unsigned int v = __hip_atomic_load(pollflag, __ATOMIC_RELAXED,
                                         __HIP_MEMORY_SCOPE_AGENT);
      if (!__all(v >= tt)) {
        __builtin_amdgcn_s_sleep(1);
        v = __hip_atomic_load(pollflag, __ATOMIC_RELAXED,
                              __HIP_MEMORY_SCOPE_AGENT);
        if (!__all(v >= tt)) {
          __builtin_amdgcn_s_sleep(2);
          v = __hip_atomic_load(pollflag, __ATOMIC_RELAXED,
                                __HIP_MEMORY_SCOPE_AGENT);
          if (!__all(v >= tt)) {
            __builtin_amdgcn_s_sleep(4);
            v = __hip_atomic_load(pollflag, __ATOMIC_RELAXED,
                                  __HIP_MEMORY_SCOPE_AGENT);
            while (!__all(v >= tt)) {
              __builtin_amdgcn_s_sleep(8);
              v = __hip_atomic_load(pollflag, __ATOMIC_RELAXED,
                                    __HIP_MEMORY_SCOPE_AGENT);
            }
          }
        }
      }
    }

    // ---- x-projection MFMAs FIRST (x-frags die before h-frags alloc) ----
    asm volatile("s_waitcnt vmcnt(0)" ::: "memory");  // x frags resident
    __builtin_amdgcn_sched_barrier(0);
    f32x4 acc0 = {}, acc1 = {};
#define XSTEP(A, W0, W1)                                                      \
  {                                                                           \
    bf16x8 av = __builtin_bit_cast(bf16x8, A);                                \
    acc0 = __builtin_amdgcn_mfma_f32_16x16x32_bf16(av, W0, acc0, 0, 0, 0);    \
    acc1 = __builtin_amdgcn_mfma_f32_16x16x32_bf16(av, W1, acc1, 0, 0, 0);    \
  }
    XSTEP(x0, wx0, wy0) XSTEP(x1, wx1, wy1) XSTEP(x2, wx2, wy2)
    XSTEP(x3, wx3, wy3) XSTEP(x4, wx4, wy4) XSTEP(x5, wx5, wy5)
    XSTEP(x6, wx6, wy6) XSTEP(x7, wx7, wy7)
#undef XSTEP

    // ---- h A-frags: 16 rows (fr) x K-slab 512 of h_{t-1}, sc0 ----
    const bf16_t* Ab = hp + (long)(m0 + fr) * H + kb + fg * 8;
    f32x4 a0, a1, a2, a3, a4, a5, a6, a7, a8, a9, a10, a11, a12, a13, a14, a15;
    asm volatile(
        "global_load_dwordx4 %0, %16, off sc0\n\t"
        "global_load_dwordx4 %1, %16, off offset:64 sc0\n\t"
        "global_load_dwordx4 %2, %16, off offset:128 sc0\n\t"
        "global_load_dwordx4 %3, %16, off offset:192 sc0\n\t"
        "global_load_dwordx4 %4, %16, off offset:256 sc0\n\t"
        "global_load_dwordx4 %5, %16, off offset:320 sc0\n\t"
        "global_load_dwordx4 %6, %16, off offset:384 sc0\n\t"
        "global_load_dwordx4 %7, %16, off offset:448 sc0\n\t"
        "global_load_dwordx4 %8, %16, off offset:512 sc0\n\t"
        "global_load_dwordx4 %9, %16, off offset:576 sc0\n\t"
        "global_load_dwordx4 %10, %16, off offset:640 sc0\n\t"
        "global_load_dwordx4 %11, %16, off offset:704 sc0\n\t"
        "global_load_dwordx4 %12, %16, off offset:768 sc0\n\t"
        "global_load_dwordx4 %13, %16, off offset:832 sc0\n\t"
        "global_load_dwordx4 %14, %16, off offset:896 sc0\n\t"
        "global_load_dwordx4 %15, %16, off offset:960 sc0"
        : "=&v"(a0), "=&v"(a1), "=&v"(a2), "=&v"(a3), "=&v"(a4), "=&v"(a5),
          "=&v"(a6), "=&v"(a7), "=&v"(a8), "=&v"(a9), "=&v"(a10), "=&v"(a11),
          "=&v"(a12), "=&v"(a13), "=&v"(a14), "=&v"(a15)
        : "v"(Ab)
        : "memory");

#define STEPX(ks, A)                                                          \
  {                                                                           \
    bf16x8 w0 = *(const bf16x8*)&Wlds[((w64 + (ks) * 4 + fg) * 32 + fr) * 8]; \
    bf16x8 w1 =                                                               \
        *(const bf16x8*)&Wlds[((w64 + (ks) * 4 + fg) * 32 + 16 + fr) * 8];    \
    bf16x8 av = __builtin_bit_cast(bf16x8, A);                                \
    acc0 = __builtin_amdgcn_mfma_f32_16x16x32_bf16(av, w0, acc0, 0, 0, 0);    \
    acc1 = __builtin_amdgcn_mfma_f32_16x16x32_bf16(av, w1, acc1, 0, 0, 0);    \
  }
    asm volatile("s_waitcnt vmcnt(8)" ::: "memory");
    __builtin_amdgcn_sched_barrier(0);  // rule #18
    STEPX(0, a0)   STEPX(1, a1)   STEPX(2, a2)   STEPX(3, a3)
    STEPX(4, a4)   STEPX(5, a5)   STEPX(6, a6)   STEPX(7, a7)
    asm volatile("s_waitcnt vmcnt(0)" ::: "memory");
    __builtin_amdgcn_sched_barrier(0);
    STEPX(8, a8)   STEPX(9, a9)   STEPX(10, a10) STEPX(11, a11)
    STEPX(12, a12) STEPX(13, a13) STEPX(14, a14) STEPX(15, a15)
#undef STEPX

    // ---- WAR guard: h-epilogue of step t-1 must have consumed sred ----
    if (t > 0) {
      while (__hip_atomic_load(sf, __ATOMIC_ACQUIRE,
                               __HIP_MEMORY_SCOPE_WORKGROUP) <
             (unsigned int)t)
        __builtin_amdgcn_s_sleep(1);
    }

    // ---- write h partials (padded stride 36) ----
#pragma unroll
    for (int rr = 0; rr < 4; ++rr) {
      sred[h][lw][(fg * 4 + rr) * 36 + fr] = acc0[rr];
      sred[h][lw][(fg * 4 + rr) * 36 + 16 + fr] = acc1[rr];
    }
    half_bar(bc, (unsigned int)(t + 1) * 4, lane);

    // ---- rotating-wave h-epilogue: reduce + b_h + relu + store + flag ----
    if (lw == ew) {
      f32x4 slo = *(const f32x4*)&sred[h][0][sidx];
      f32x4 shi = *(const f32x4*)&sred[h][0][sidx + 4];
#pragma unroll
      for (int ww = 1; ww < 4; ++ww) {
        slo = slo + *(const f32x4*)&sred[h][ww][sidx];
        shi = shi + *(const f32x4*)&sred[h][ww][sidx + 4];
      }
      bf16x8 o;
#pragma unroll
      for (int c = 0; c < 4; ++c) {
        float v0 = slo[c] + bhlo[c];
        float v1 = shi[c] + bhhi[c];
        o[c] = (bf16_t)(v0 > 0.f ? v0 : 0.f);
        o[c + 4] = (bf16_t)(v1 > 0.f ? v1 : 0.f);
      }
      const bf16_t* zp = z + zoffW;
      {
        f32x4 ov = __builtin_bit_cast(f32x4, o);
        asm volatile("global_store_dwordx4 %0, %1, off sc0 sc1" ::"v"(zp),
                     "v"(ov)
                     : "memory");
      }
      asm volatile("s_waitcnt vmcnt(0)" ::: "memory");  // tile visible in L3
      if (lane == 0) {
        __hip_atomic_store(myflag, (unsigned int)(t + 1), __ATOMIC_RELAXED,
                           __HIP_MEMORY_SCOPE_AGENT);
        __hip_atomic_store(sf, (unsigned int)(t + 1), __ATOMIC_RELEASE,
                           __HIP_MEMORY_SCOPE_WORKGROUP);
      }
    }

    // ======== FUSED Q-PROJECTION: out_{t-1} = h_{t-1} @ W_hq + b_q ========
    if (t > 0) {
      f32x4 qacc = {};
#define QSTEP(A, QW)                                                          \
  qacc = __builtin_amdgcn_mfma_f32_16x16x32_bf16(                             \
      __builtin_bit_cast(bf16x8, A), QW, qacc, 0, 0, 0);
      QSTEP(a0, q0)   QSTEP(a1, q1)   QSTEP(a2, q2)   QSTEP(a3, q3)
      QSTEP(a4, q4)   QSTEP(a5, q5)   QSTEP(a6, q6)   QSTEP(a7, q7)
      QSTEP(a8, q8)   QSTEP(a9, q9)   QSTEP(a10, q10) QSTEP(a11, q11)
      QSTEP(a12, q12) QSTEP(a13, q13) QSTEP(a14, q14) QSTEP(a15, q15)
#undef QSTEP
      while (__hip_atomic_load(qf, __ATOMIC_ACQUIRE,
                               __HIP_MEMORY_SCOPE_WORKGROUP) <
             (unsigned int)(t - 1))
        __builtin_amdgcn_s_sleep(1);
#pragma unroll
      for (int rr = 0; rr < 4; ++rr)
        qred[h][lw][(fg * 4 + rr) * 20 + fr] = (bf16_t)qacc[rr];
      half_bar(qc, (unsigned int)t * 4, lane);

      if (lw == ew2) {
        f32x4 s = bqv;
#pragma unroll
        for (int ww = 0; ww < 4; ++ww)
#pragma unroll
          for (int j = 0; j < 4; ++j)
            s[j] += (float)qred[h][ww][qrow * 20 + qc4 + j];
        float* op = out + ((long)(t - 1) * 128 + m0 + qrow) * 1024 + qcol0 + qc4;
        *(f32x4*)op = s;
        if (lane == 0)
          __hip_atomic_store(qf, (unsigned int)t, __ATOMIC_RELEASE,
                             __HIP_MEMORY_SCOPE_WORKGROUP);
      }
    }
  }

  // ======== post-loop: out_255 from h_255 ========
  {
    const unsigned int tt = 256u;
    unsigned int v;
    do {
      v = __hip_atomic_load(pollflag, __ATOMIC_RELAXED,
                            __HIP_MEMORY_SCOPE_AGENT);
      if (__all(v >= tt)) break;
      __builtin_amdgcn_s_sleep(2);
    } while (true);

    const bf16_t* hp = Hbuf + 255L * BH;
    const bf16_t* Ab = hp + (long)(m0 + fr) * H + kb + fg * 8;
    f32x4 a0, a1, a2, a3, a4, a5, a6, a7, a8, a9, a10, a11, a12, a13, a14, a15;
    asm volatile(
        "global_load_dwordx4 %0, %16, off sc0\n\t"
        "global_load_dwordx4 %1, %16, off offset:64 sc0\n\t"
        "global_load_dwordx4 %2, %16, off offset:128 sc0\n\t"
        "global_load_dwordx4 %3, %16, off offset:192 sc0\n\t"
        "global_load_dwordx4 %4, %16, off offset:256 sc0\n\t"
        "global_load_dwordx4 %5, %16, off offset:320 sc0\n\t"
        "global_load_dwordx4 %6, %16, off offset:384 sc0\n\t"
        "global_load_dwordx4 %7, %16, off offset:448 sc0\n\t"
        "global_load_dwordx4 %8, %16, off offset:512 sc0\n\t"
        "global_load_dwordx4 %9, %16, off offset:576 sc0\n\t"
        "global_load_dwordx4 %10, %16, off offset:640 sc0\n\t"
        "global_load_dwordx4 %11, %16, off offset:704 sc0\n\t"
        "global_load_dwordx4 %12, %16, off offset:768 sc0\n\t"
        "global_load_dwordx4 %13, %16, off offset:832 sc0\n\t"
        "global_load_dwordx4 %14, %16, off offset:896 sc0\n\t"
        "global_load_dwordx4 %15, %16, off offset:960 sc0\n\t"
        "s_waitcnt vmcnt(0)"
        : "=&v"(a0), "=&v"(a1), "=&v"(a2), "=&v"(a3), "=&v"(a4), "=&v"(a5),
          "=&v"(a6), "=&v"(a7), "=&v"(a8), "=&v"(a9), "=&v"(a10), "=&v"(a11),
          "=&v"(a12), "=&v"(a13), "=&v"(a14), "=&v"(a15)
        : "v"(Ab)
        : "memory");
    __builtin_amdgcn_sched_barrier(0);

    f32x4 qacc = {};
#define QSTEP(A, QW)                                                          \
  qacc = __builtin_amdgcn_mfma_f32_16x16x32_bf16(                             \
      __builtin_bit_cast(bf16x8, A), QW, qacc, 0, 0, 0);
    QSTEP(a0, q0)   QSTEP(a1, q1)   QSTEP(a2, q2)   QSTEP(a3, q3)
    QSTEP(a4, q4)   QSTEP(a5, q5)   QSTEP(a6, q6)   QSTEP(a7, q7)
    QSTEP(a8, q8)   QSTEP(a9, q9)   QSTEP(a10, q10) QSTEP(a11, q11)
    QSTEP(a12, q12) QSTEP(a13, q13) QSTEP(a14, q14) QSTEP(a15, q15)
#undef QSTEP
    while (__hip_atomic_load(qf, __ATOMIC_ACQUIRE,
                             __HIP_MEMORY_SCOPE_WORKGROUP) < 255u)
      __builtin_amdgcn_s_sleep(1);
#pragma unroll
    for (int rr = 0; rr < 4; ++rr)
      qred[h][lw][(fg * 4 + rr) * 20 + fr] = (bf16_t)qacc[rr];
    half_bar(qc, 256u * 4, lane);

    if (lw == ((256 + 2) & 3)) {
      f32x4 s = bqv;
#pragma unroll
      for (int ww = 0; ww < 4; ++ww)
#pragma unroll
        for (int j = 0; j < 4; ++j)
          s[j] += (float)qred[h][ww][qrow * 20 + qc4 + j];
      float* op = out + (255L * 128 + m0 + qrow) * 1024 + qcol0 + qc4;
      *(f32x4*)op = s;
    }
  }
}

// ---------------------------------------------------------------------------
extern "C" void kernel_launch(void* const* d_in, const int* in_sizes, int n_in,
                              void* d_out, int out_size, void* d_ws,
                              size_t ws_size, hipStream_t stream) {
  const float* x   = (const float*)d_in[0];  // (T,B,D)
  const float* h0  = (const float*)d_in[1];  // (B,H)
  const float* Wxh = (const float*)d_in[2];  // (D,H)
  const float* Whh = (const float*)d_in[3];  // (H,H)
  const float* bh  = (const float*)d_in[4];  // (H,)
  const float* Whq = (const float*)d_in[5];  // (H,Q)
  const float* bq  = (const float*)d_in[6];  // (Q,)
  float* out = (float*)d_out;

  const int T = 256, B = 128, D = 1024, H = 2048, Q = 1024;
  const long MB = (long)T * B;  // 32768

  char* ws = (char*)d_ws;
  unsigned int* flags = (unsigned int*)ws;  ws += 512 * 64;  // padded flags
  bf16_t* x_bf = (bf16_t*)ws;  ws += MB * D * 2;             // 64 MiB
  bf16_t* Hbuf = (bf16_t*)ws;  ws += MB * H * 2;             // 128 MiB (h)
  bf16_t* h0bf = (bf16_t*)ws;  ws += (long)B * H * 2;
  bf16_t* WxhT = (bf16_t*)ws;  ws += (long)H * D * 2;
  bf16_t* WhhT = (bf16_t*)ws;  ws += (long)H * H * 2;
  bf16_t* WhqT = (bf16_t*)ws;  ws += (long)Q * H * 2;

  hipMemsetAsync(flags, 0, 512 * 64, stream);

  // --- convert inputs to bf16 (weights transposed to N x K) ---
  conv_f32_bf16<<<(int)(MB * D / 8 / 256), 256, 0, stream>>>(x, x_bf, MB * D);
  conv_f32_bf16<<<(int)((long)B * H / 8 / 256), 256, 0, stream>>>(h0, h0bf,
                                                                  (long)B * H);
  transpose_conv<<<dim3(H / 32, D / 32), dim3(32, 8), 0, stream>>>(Wxh, WxhT, D, H);
  transpose_conv<<<dim3(H / 32, H / 32), dim3(32, 8), 0, stream>>>(Whh, WhhT, H, H);
  transpose_conv<<<dim3(Q / 32, H / 32), dim3(32, 8), 0, stream>>>(Whq, WhqT, H, Q);

  // --- EVERYTHING ELSE in ONE persistent kernel (Z-GEMM + recurrence +
  //     Q-projection all fused; GEMM1 and GEMM2 launches deleted) ---
  rnn_persistent15<<<256, 512, 0, stream>>>(h0bf, x_bf, Hbuf, WhhT, WxhT, bh,
                                            WhqT, bq, out, flags);

  // --- final h (fp32) appended after (T*B, Q) block ---
  conv_bf16_f32<<<(int)((long)B * H / 256), 256, 0, stream>>>(
      Hbuf + (long)(T - 1) * B * H, out + MB * Q, (long)B * H);
}